// Round 9
// baseline (241.119 us; speedup 1.0000x reference)
//
#include <hip/hip_runtime.h>
#include <hip/hip_bf16.h>

typedef __attribute__((ext_vector_type(8))) short bf16x8;   // 8 bf16 = 4 VGPRs
typedef __attribute__((ext_vector_type(4))) float f32x4;    // MFMA C/D frag

#define Qn 4096
#define Mn 8192
#define Dn 128
#define NWA 4                    // waves per block
#define QB 128                   // q-rows per block (32 per wave, 2 subtiles)
#define MSPLIT 16                // M split (2 slices per XCD)
#define BCOLS (Mn / MSPLIT)      // 512 cols per block
#define TILE 64                  // m-cols per staged tile
#define NIT (BCOLS / TILE)       // 8 iterations per block

__device__ __forceinline__ unsigned short f2bf(float x) {
  __hip_bfloat16 h = __float2bfloat16(x);
  return *reinterpret_cast<unsigned short*>(&h);
}

// Async global->LDS, 16B per lane. LDS dest is WAVE-UNIFORM base (HW adds
// lane*16); global src is per-lane.
__device__ __forceinline__ void gld_lds16(const void* g, void* l) {
  __builtin_amdgcn_global_load_lds(
      (const __attribute__((address_space(1))) unsigned int*)g,
      (__attribute__((address_space(3))) unsigned int*)l, 16, 0, 0);
}

__global__ void zero_kernel(float4* __restrict__ p, int n4) {
  int i = blockIdx.x * blockDim.x + threadIdx.x;
  if (i < n4) p[i] = make_float4(0.f, 0.f, 0.f, 0.f);
}

// Q * (1/sqrt(D)) -> bf16, vectorized
__global__ void cast_q(const float4* __restrict__ Q4, ushort4* __restrict__ Qs) {
  int i = blockIdx.x * blockDim.x + threadIdx.x;   // < Qn*Dn/4
  const float s = 0.088388347648318447f;           // 1/sqrt(128)
  float4 q = Q4[i];
  Qs[i] = make_ushort4(f2bf(q.x * s), f2bf(q.y * s), f2bf(q.z * s), f2bf(q.w * s));
}

// Swizzle K into MFMA-fragment-major bf16 layouts (proven R5). Key property:
// a 64-col tile at 64-aligned m0 is a CONTIGUOUS 16KB region at byte offset
// m0*256 in both arrays -> staged into LDS linearly; fragment reads use the
// same in-tile offsets:
//  Kswz in-tile frag: ((a*4+kk)*64 + lane)*8 shorts  (a = m-subtile 0..3)
//  Vswz in-tile frag: ((n*2+kk)*64 + lane)*8 shorts  (n = d-subtile 0..7)
__global__ __launch_bounds__(256) void swz_kernel(const float* __restrict__ K,
                                                  unsigned short* __restrict__ Kswz,
                                                  unsigned short* __restrict__ Vswz) {
  __shared__ __align__(16) unsigned short T[64][72];   // 64m x 64d tile, bf16, padded
  const int m0 = blockIdx.x * 64, d0 = blockIdx.y * 64;
  const int t = threadIdx.x;
  const int r = t >> 4, c4 = (t & 15) * 4;
#pragma unroll
  for (int rr = 0; rr < 64; rr += 16) {
    float4 v = *reinterpret_cast<const float4*>(&K[(size_t)(m0 + r + rr) * Dn + d0 + c4]);
    ushort4 b = make_ushort4(f2bf(v.x), f2bf(v.y), f2bf(v.z), f2bf(v.w));
    *reinterpret_cast<ushort4*>(&T[r + rr][c4]) = b;
  }
  __syncthreads();
#pragma unroll
  for (int rep = 0; rep < 2; ++rep) {
    int w = t + rep * 256;
    int ml = w >> 3, oct = w & 7;
    uint4 val = *reinterpret_cast<uint4*>(&T[ml][oct * 8]);
    int m = m0 + ml, d = d0 + oct * 8;
    int g = m >> 4, l = m & 15, kk = d >> 5, quad = (d >> 3) & 3;
    *reinterpret_cast<uint4*>(&Kswz[(size_t)(((g * 4 + kk) * 64) + quad * 16 + l) * 8]) = val;
  }
#pragma unroll
  for (int rep = 0; rep < 2; ++rep) {
    int w = t + rep * 256;
    int dl = w >> 3, moct = w & 7;
    unsigned short tmp[8];
#pragma unroll
    for (int j = 0; j < 8; ++j) tmp[j] = T[moct * 8 + j][dl];
    int d = d0 + dl, m = m0 + moct * 8;
    int np = d >> 4, lB = d & 15, mt = m >> 6, mm = m & 63, kk2 = mm >> 5, qB = (mm >> 3) & 3;
    *reinterpret_cast<uint4*>(
        &Vswz[(size_t)((((mt * 8 + np) * 2 + kk2) * 64) + qB * 16 + lB) * 8]) =
        *reinterpret_cast<uint4*>(tmp);
  }
}

// R9: 32 q-rows per wave (2x16 subtiles). DS ledger said K/V LDS reads were
// the largest attn term (~26us/CU): every wave reads the full 16KB K + 16KB
// V tile per iter but covered only 16 q-rows. K/V fragments depend only on
// (a,kk,lane) -- NOT on q -- so a wave owning 32 rows reads each fragment
// ONCE and issues 2 MFMAs (aq0/aq1). Halves DS per q-row. QB 64->128 also
// halves K/V global re-staging (scales as Qn/QB): 256->128MB total.
//
// MSPLIT 16 keeps grid=512 = 2 blocks/CU (R6: 1 block/CU exposes stage
// latency; R7: MSPLIT-16 atomic doubling is ~free). LDS fits 2 blocks/CU
// via the R6/R7-proven W/P union: W -> regs wv[32], lgkm fence, P bf16
// [32][72] overwrites the W region. K 16K + V 16K + W 4x8K = 64KB exact.
// R6's regression is attributed to the 8-wave convoy + 1 block/CU, both
// avoided here (4 waves, 2 blocks/CU).
//
// W chunk XOR swizzle: chunk i covers rows 4i..4i+3; source col pre-XOR
// key (i&3)*16; read key quad*16 (row>>2 = sub*4+quad ≡ quad mod 4) ->
// keys match; 2-way bank alias (free). gld_lds dest stays linear.
//
// VGPR: aq32 + O64 + S32 + wv32 + temps ~= 185 live; (2,2) = 256-reg
// budget, no spill (R1/R3: pins >=4 waves/SIMD spill big live sets).
// Tripwire: WRITE_SIZE >> 40MB => spill => revert.
__global__ __launch_bounds__(256) __attribute__((amdgpu_waves_per_eu(2, 2)))
void attn_kernel(const float* __restrict__ W,
                 const unsigned short* __restrict__ Qs,
                 const unsigned short* __restrict__ Kswz,
                 const unsigned short* __restrict__ Vswz,
                 float* __restrict__ Oacc,
                 float* __restrict__ Lacc) {
  __shared__ __align__(16) unsigned short Klds[16 * 64 * 8];   // 16KB K tile
  __shared__ __align__(16) unsigned short Vlds[16 * 64 * 8];   // 16KB V tile
  __shared__ __align__(16) unsigned char  WP[NWA][8192];       // 32KB W fp32 / P bf16 union

  const int tid  = threadIdx.x;
  const int wave = tid >> 6;
  const int lane = tid & 63;
  const int l    = lane & 15;
  const int quad = lane >> 4;
  const int b    = blockIdx.x;
  const int qb   = (b >> 4) * QB;      // 32 q-blocks
  const int mbeg = (b & 15) * BCOLS;   // m-slice (2 per XCD)
  const int qw   = qb + wave * 32;     // this wave's 32 q-rows

  // Persistent Q A-fragments: two 16-row subtiles.
  bf16x8 aq[2][4];
#pragma unroll
  for (int sub = 0; sub < 2; ++sub) {
    const unsigned short* qrow = Qs + (size_t)(qw + sub * 16 + l) * Dn + quad * 8;
#pragma unroll
    for (int kk = 0; kk < 4; ++kk)
      aq[sub][kk] = *reinterpret_cast<const bf16x8*>(qrow + 32 * kk);
  }

  f32x4 O[2][8];
#pragma unroll
  for (int sub = 0; sub < 2; ++sub)
#pragma unroll
    for (int n = 0; n < 8; ++n) O[sub][n] = (f32x4){0.f, 0.f, 0.f, 0.f};
  float lsum[2][4] = {{0.f, 0.f, 0.f, 0.f}, {0.f, 0.f, 0.f, 0.f}};

  for (int it = 0; it < NIT; ++it) {
    const int m0 = mbeg + it * TILE;
    __syncthreads();   // prev compute's LDS reads done before overwrite

    // Stage K/V tiles: 16KB each = 16 chunks of 1KB; wave stages 4+4.
    {
      const unsigned short* ksrc = Kswz + (size_t)m0 * 128;
      const unsigned short* vsrc = Vswz + (size_t)m0 * 128;
#pragma unroll
      for (int i = 0; i < 4; ++i) {
        const int c = wave * 4 + i;                 // 1KB chunk 0..15
        gld_lds16(ksrc + (size_t)c * 512 + lane * 8, &Klds[c * 512]);
        gld_lds16(vsrc + (size_t)c * 512 + lane * 8, &Vlds[c * 512]);
      }
    }
    // Stage this wave's W tile: 32 rows x 64 cols fp32 (8KB = 8 chunks),
    // row-major with source-col XOR key (i&3)*16. Lane: row 4i+(lane>>4),
    // cols ((lane&15)*4)^((i&3)*16) .. +3 (XOR preserves the float4).
#pragma unroll
    for (int i = 0; i < 8; ++i) {
      const float* wsrc = &W[(size_t)(qw + i * 4 + (lane >> 4)) * Mn + m0 +
                             (((lane & 15) * 4) ^ ((i & 3) * 16))];
      gld_lds16(wsrc, &WP[wave][i * 1024]);
    }
    __syncthreads();   // vmcnt(0) drain + barrier: tiles ready

    // QK^T: bk read ONCE per (a,kk), used by both q-subtiles.
    f32x4 S[2][4];
#pragma unroll
    for (int sub = 0; sub < 2; ++sub)
#pragma unroll
      for (int a = 0; a < 4; ++a) S[sub][a] = (f32x4){0.f, 0.f, 0.f, 0.f};
#pragma unroll
    for (int a = 0; a < 4; ++a)
#pragma unroll
      for (int kk = 0; kk < 4; ++kk) {
        bf16x8 bk = *reinterpret_cast<const bf16x8*>(
            &Klds[((a * 4 + kk) * 64 + lane) * 8]);
        S[0][a] = __builtin_amdgcn_mfma_f32_16x16x32_bf16(aq[0][kk], bk, S[0][a], 0, 0, 0);
        S[1][a] = __builtin_amdgcn_mfma_f32_16x16x32_bf16(aq[1][kk], bk, S[1][a], 0, 0, 0);
      }

    // W -> regs (rows sub*16+quad*4+r, col (16a+l)^(quad*16)), then fence
    // so P may overwrite the W region.
    float wv[2][16];
#pragma unroll
    for (int sub = 0; sub < 2; ++sub)
#pragma unroll
      for (int a = 0; a < 4; ++a)
#pragma unroll
        for (int r = 0; r < 4; ++r)
          wv[sub][a * 4 + r] = *reinterpret_cast<const float*>(
              &WP[wave][(size_t)(((sub * 16 + quad * 4 + r) * 64) +
                                 ((16 * a + l) ^ (quad * 16))) * 4]);
    asm volatile("s_waitcnt lgkmcnt(0)" ::: "memory");   // W landed; region reusable

    // P = exp(S*W) -> bf16 into the (now dead) W region, padded [32][72].
    unsigned short* P = reinterpret_cast<unsigned short*>(&WP[wave][0]);
#pragma unroll
    for (int sub = 0; sub < 2; ++sub)
#pragma unroll
      for (int a = 0; a < 4; ++a)
#pragma unroll
        for (int r = 0; r < 4; ++r) {
          float p = __expf(S[sub][a][r] * wv[sub][a * 4 + r]);
          lsum[sub][r] += p;
          P[(sub * 16 + quad * 4 + r) * 72 + 16 * a + l] = f2bf(p);
        }
    asm volatile("s_waitcnt lgkmcnt(0)" ::: "memory");   // P visible to own wave

    // PV: bv read ONCE per (n,kk), used by both q-subtiles.
#pragma unroll
    for (int kk = 0; kk < 2; ++kk) {
      bf16x8 pa0 = *reinterpret_cast<const bf16x8*>(
          &P[(0 * 16 + l) * 72 + 32 * kk + quad * 8]);
      bf16x8 pa1 = *reinterpret_cast<const bf16x8*>(
          &P[(1 * 16 + l) * 72 + 32 * kk + quad * 8]);
#pragma unroll
      for (int n = 0; n < 8; ++n) {
        bf16x8 bv = *reinterpret_cast<const bf16x8*>(
            &Vlds[((n * 2 + kk) * 64 + lane) * 8]);
        O[0][n] = __builtin_amdgcn_mfma_f32_16x16x32_bf16(pa0, bv, O[0][n], 0, 0, 0);
        O[1][n] = __builtin_amdgcn_mfma_f32_16x16x32_bf16(pa1, bv, O[1][n], 0, 0, 0);
      }
    }
  }

  // lsum reduce across the 16 l-lanes of each quad (m-cols live on l).
#pragma unroll
  for (int sub = 0; sub < 2; ++sub)
#pragma unroll
    for (int r = 0; r < 4; ++r)
#pragma unroll
      for (int off = 1; off < 16; off <<= 1)
        lsum[sub][r] += __shfl_xor(lsum[sub][r], off, 64);

  // Waves own distinct q-rows: no cross-wave combine. Cross-block (MSPLIT)
  // combine via device atomics.
#pragma unroll
  for (int sub = 0; sub < 2; ++sub) {
#pragma unroll
    for (int n = 0; n < 8; ++n)
#pragma unroll
      for (int r = 0; r < 4; ++r)
        atomicAdd(&Oacc[(size_t)(qw + sub * 16 + quad * 4 + r) * Dn + 16 * n + l],
                  O[sub][n][r]);
    if (l == 0)
#pragma unroll
      for (int r = 0; r < 4; ++r)
        atomicAdd(&Lacc[qw + sub * 16 + quad * 4 + r], lsum[sub][r]);
  }
}

__global__ void finalize_kernel(const float4* __restrict__ Oacc,
                                const float* __restrict__ Lacc,
                                float4* __restrict__ out) {
  int i = blockIdx.x * blockDim.x + threadIdx.x;   // < Qn*Dn/4
  float4 o = Oacc[i];
  float inv = 1.0f / Lacc[i >> 5];                 // 32 float4 per row
  out[i] = make_float4(o.x * inv, o.y * inv, o.z * inv, o.w * inv);
}

extern "C" void kernel_launch(void* const* d_in, const int* in_sizes, int n_in,
                              void* d_out, int out_size, void* d_ws, size_t ws_size,
                              hipStream_t stream) {
  const float* Q = (const float*)d_in[0];          // [4096,128]
  const float* K = (const float*)d_in[1];          // [8192,128]
  const float* W = (const float*)d_in[2];          // [4096,8192]
  float* out = (float*)d_out;                      // [4096,128]

  unsigned short* Qs   = (unsigned short*)d_ws;               // 1 MB
  unsigned short* Kswz = Qs + (size_t)Qn * Dn;                // 2 MB
  unsigned short* Vswz = Kswz + (size_t)Mn * Dn;              // 2 MB
  float* Oacc = (float*)(Vswz + (size_t)Mn * Dn);             // 2 MB
  float* Lacc = Oacc + (size_t)Qn * Dn;                       // 16 KB (total 7.02 MB)

  int n4 = (Qn * Dn + Qn) / 4;                                // Oacc + Lacc zeroing
  zero_kernel<<<(n4 + 255) / 256, 256, 0, stream>>>((float4*)Oacc, n4);

  cast_q<<<(Qn * Dn / 4) / 256, 256, 0, stream>>>((const float4*)Q, (ushort4*)Qs);
  swz_kernel<<<dim3(Mn / 64, Dn / 64), 256, 0, stream>>>(K, Kswz, Vswz);
  attn_kernel<<<(Qn / QB) * MSPLIT, 256, 0, stream>>>(W, Qs, Kswz, Vswz, Oacc, Lacc);
  finalize_kernel<<<(Qn * Dn / 4) / 256, 256, 0, stream>>>(
      (const float4*)Oacc, Lacc, (float4*)out);
}